// Round 5
// baseline (137.768 us; speedup 1.0000x reference)
//
#include <hip/hip_runtime.h>
#include <math.h>

#define NB 2048
#define LL 200
#define DD 64
#define CC 9
#define HH 16
#define NW 4

// Fused per-user kernel. e-rows staged once in LDS (XOR-swizzled), then:
// score MLP -> masked softmax -> gvec -> top attention -> output.
__global__ __launch_bounds__(256) void din_fused(
    const int* __restrict__ user_inputs,
    const int* __restrict__ record_inputs,
    const int* __restrict__ item_inputs,
    const int* __restrict__ item_cat,
    const float* __restrict__ user_emb,
    const float* __restrict__ item_emb,
    const float* __restrict__ W1,
    const float* __restrict__ b1,
    const float* __restrict__ W2,
    const float* __restrict__ b2,
    const float* __restrict__ Wt1,
    const float* __restrict__ bt1,
    const float* __restrict__ Wt2,
    const float* __restrict__ bt2,
    float* __restrict__ out)
{
  const int b = blockIdx.x;
  const int t = threadIdx.x;
  const int wave = t >> 6, lane = t & 63;

  __shared__ float4 e_lds[LL * 16];      // 51.2 KB, swizzled: slot = i ^ (row&7)
  __shared__ float  u_s[DD];
  __shared__ float  pre_s[CC][HH];
  __shared__ int    srow[LL];
  __shared__ float  s_s[LL];
  __shared__ float  w_s[LL];
  __shared__ int    cstart[CC + 1];
  __shared__ int    wcnt[NW][CC];
  __shared__ float  cinv[CC];
  __shared__ float  gvec_s[CC][DD];
  __shared__ float  h2_s[CC][HH];
  __shared__ float  w2_s[CC];

  // ---- Phase A: loads + ballot-based stable counting sort ----
  int r = -1, c0 = -1;
  if (t < LL) {
    r = record_inputs[b * LL + t];
    if (r >= 0) c0 = item_cat[r];
  }
  if (t < DD) u_s[t] = user_emb[(size_t)user_inputs[b] * DD + t];

  int myrank = 0;
  #pragma unroll
  for (int c = 0; c < CC; ++c) {
    unsigned long long m = __ballot(c0 == c);
    if (lane == 0) wcnt[wave][c] = __popcll(m);
    if (c0 == c) myrank = __popcll(m & ((1ULL << lane) - 1ULL));
  }
  __syncthreads();

  if (t == 0) {
    int acc = 0;
    #pragma unroll
    for (int c = 0; c < CC; ++c) {
      cstart[c] = acc;
      acc += wcnt[0][c] + wcnt[1][c] + wcnt[2][c] + wcnt[3][c];
    }
    cstart[CC] = acc;
  }
  if (t < CC * HH) {   // pre = b1 + W1u . u
    int c = t / HH, j = t % HH;
    const float* wp = &W1[(size_t)(c * HH + j) * (2 * DD)];
    float acc = b1[c * HH + j];
    #pragma unroll 8
    for (int d = 0; d < DD; ++d) acc += wp[d] * u_s[d];
    pre_s[c][j] = acc;
  }
  __syncthreads();

  // stable scatter into sorted order
  if (c0 >= 0) {
    int off = cstart[c0];
    for (int w = 0; w < wave; ++w) off += wcnt[w][c0];
    srow[off + myrank] = r;
  }
  __syncthreads();

  const int nvalid = cstart[CC];

  // ---- Phase B: stage e rows into LDS (swizzled), 16 chunks/row ----
  for (int k = t; k < nvalid * 16; k += 256) {
    int row = k >> 4, i = k & 15;
    e_lds[(row << 4) + (i ^ (row & 7))] =
        ((const float4*)&item_emb[(size_t)srow[row] * DD])[i];
  }
  __syncthreads();

  // ---- Phase C: per-item MLP score from LDS ----
  if (t < nvalid) {
    int c = 0;
    #pragma unroll
    for (int q = 0; q < CC - 1; ++q) c += (t >= cstart[q + 1]) ? 1 : 0;
    const float4* wbase = (const float4*)&W1[(size_t)c * HH * (2 * DD) + DD];

    float acc[HH];
    #pragma unroll
    for (int j = 0; j < HH; ++j) acc[j] = pre_s[c][j];

    #pragma unroll
    for (int i = 0; i < 16; ++i) {
      float4 ev = e_lds[(t << 4) + (i ^ (t & 7))];
      #pragma unroll
      for (int j = 0; j < HH; ++j) {
        float4 wv = wbase[j * 32 + i];
        acc[j] += wv.x * ev.x + wv.y * ev.y + wv.z * ev.z + wv.w * ev.w;
      }
    }
    float s = b2[c];
    #pragma unroll
    for (int j = 0; j < HH; ++j) s += W2[c * HH + j] * fmaxf(acc[j], 0.f);
    s_s[t] = s;
  }
  __syncthreads();

  // ---- Phase D: masked softmax per category ----
  if (t < CC) {
    int i0 = cstart[t], i1 = cstart[t + 1];
    float m = -INFINITY;
    for (int i = i0; i < i1; ++i) m = fmaxf(m, s_s[i]);
    float sum = 0.f;
    for (int i = i0; i < i1; ++i) {
      float z = expf(s_s[i] - m);
      w_s[i] = z;
      sum += z;
    }
    cinv[t] = 1.f / fmaxf(sum, 1e-30f);
  }
  __syncthreads();

  // ---- Phase E: gvec from LDS (wave per category, lane = d) ----
  {
    const float* e_f = (const float*)e_lds;
    for (int c = wave; c < CC; c += NW) {
      int i0 = cstart[c], i1 = cstart[c + 1];
      float acc = 0.f;
      for (int i = i0; i < i1; ++i) {
        int idx = (i << 6) + (((((unsigned)lane >> 2) ^ (i & 7)) << 2) | (lane & 3));
        acc += w_s[i] * e_f[idx];
      }
      gvec_s[c][lane] = acc * cinv[c];   // empty cat -> 0
    }
  }
  __syncthreads();

  // ---- Phase F: top-level attention ----
  if (t < CC * HH) {
    int c = t / HH, j = t % HH;
    const float* wp = &Wt1[(size_t)j * (2 * DD)];
    float acc = bt1[j];
    #pragma unroll 8
    for (int d = 0; d < DD; ++d) acc += wp[d] * u_s[d];
    #pragma unroll 8
    for (int d = 0; d < DD; ++d) acc += wp[DD + d] * gvec_s[c][d];
    h2_s[c][j] = fmaxf(acc, 0.f);
  }
  __syncthreads();

  if (t == 0) {
    float s2[CC];
    float m = -INFINITY;
    #pragma unroll
    for (int c = 0; c < CC; ++c) {
      float acc = bt2[0];
      #pragma unroll
      for (int j = 0; j < HH; ++j) acc += Wt2[j] * h2_s[c][j];
      s2[c] = acc;
      if (cstart[c + 1] > cstart[c]) m = fmaxf(m, acc);
    }
    if (m == -INFINITY) m = 0.f;
    float sum = 0.f;
    float z2[CC];
    #pragma unroll
    for (int c = 0; c < CC; ++c) {
      z2[c] = (cstart[c + 1] > cstart[c]) ? expf(s2[c] - m) : 0.f;
      sum += z2[c];
    }
    float inv = 1.f / fmaxf(sum, 1e-30f);
    #pragma unroll
    for (int c = 0; c < CC; ++c) w2_s[c] = z2[c] * inv;
  }
  __syncthreads();

  // ---- Phase G: hybrid . target_item ----
  if (t < DD) {
    float hy = 0.f;
    #pragma unroll
    for (int c = 0; c < CC; ++c) hy += w2_s[c] * gvec_s[c][t];
    float ti = item_emb[(size_t)item_inputs[b] * DD + t];
    float prod = hy * ti;
    #pragma unroll
    for (int off = 32; off > 0; off >>= 1)
      prod += __shfl_down(prod, off, 64);
    if (t == 0) out[b] = prod;
  }
}

extern "C" void kernel_launch(void* const* d_in, const int* in_sizes, int n_in,
                              void* d_out, int out_size, void* d_ws, size_t ws_size,
                              hipStream_t stream) {
  const int*   user_inputs   = (const int*)d_in[0];
  const int*   record_inputs = (const int*)d_in[1];
  const int*   item_inputs   = (const int*)d_in[2];
  const int*   item_cat      = (const int*)d_in[3];
  const float* user_emb      = (const float*)d_in[4];
  const float* item_emb      = (const float*)d_in[5];
  const float* W1            = (const float*)d_in[6];
  const float* b1            = (const float*)d_in[7];
  const float* W2            = (const float*)d_in[8];
  const float* b2            = (const float*)d_in[9];
  const float* Wt1           = (const float*)d_in[10];
  const float* bt1           = (const float*)d_in[11];
  const float* Wt2           = (const float*)d_in[12];
  const float* bt2           = (const float*)d_in[13];
  float* out = (float*)d_out;

  din_fused<<<NB, 256, 0, stream>>>(user_inputs, record_inputs, item_inputs, item_cat,
                                    user_emb, item_emb, W1, b1, W2, b2,
                                    Wt1, bt1, Wt2, bt2, out);
}